// Round 6
// baseline (85.727 us; speedup 1.0000x reference)
//
#include <hip/hip_runtime.h>
#include <stdint.h>

#define T_ROWS 256
#define KF 4096
#define OF 11008
#define WROW 2240   // packed W row: 1856 B (4-bit, +8 nibbles) + 256 B (6-bit i8) + 128 B (8-bit i8)
// grouped (dest) segment layout: [0,3712) 4-bit, [3712,3968) 6-bit, [3968,4096) 8-bit

typedef int   v4i __attribute__((ext_vector_type(4)));
typedef float v4f __attribute__((ext_vector_type(4)));
typedef unsigned int u32;

typedef const __attribute__((address_space(1))) uint8_t* gptr_t;
typedef __attribute__((address_space(3))) uint8_t* lptr_t;

#define KEEPF(x) asm volatile("" :: "v"(x))
#define KEEPI(x) asm volatile("" :: "v"(x))

// ---------------------------------------------------------------------------
// Kernel 0: stable partition of source columns by segment (wave shfl-scans).
// ---------------------------------------------------------------------------
__global__ __launch_bounds__(256) void perm_k(const int* __restrict__ idx,
                                              int* __restrict__ src_of) {
    __shared__ uint8_t g[KF];
    __shared__ int cnt[3][256];
    __shared__ int exc[3][256];
    const int t = threadIdx.x;
    for (int i = 0; i < 16; ++i) {
        int p = t * 16 + i;
        int seg = p < 3712 ? 0 : (p < 3968 ? 1 : 2);
        g[idx[p]] = (uint8_t)seg;
    }
    __syncthreads();
    int c0 = 0, c1 = 0, c2 = 0;
    for (int i = 0; i < 16; ++i) {
        int s = g[t * 16 + i];
        c0 += (s == 0); c1 += (s == 1); c2 += (s == 2);
    }
    cnt[0][t] = c0; cnt[1][t] = c1; cnt[2][t] = c2;
    __syncthreads();
    if (t < 192) {                       // wave s scans segment s
        int s = t >> 6, l = t & 63;
        int run = 0;
        for (int j = 0; j < 4; ++j) {
            int x = cnt[s][j * 64 + l];
            int inc = x;
#pragma unroll
            for (int off = 1; off < 64; off <<= 1) {
                int y = __shfl_up(inc, off);
                if (l >= off) inc += y;
            }
            exc[s][j * 64 + l] = run + inc - x;
            run += __shfl(inc, 63);
        }
    }
    __syncthreads();
    int off0 = exc[0][t], off1 = 3712 + exc[1][t], off2 = 3968 + exc[2][t];
    for (int i = 0; i < 16; ++i) {
        int c = t * 16 + i;
        int s = g[c];
        int d = (s == 0) ? off0++ : (s == 1) ? off1++ : off2++;
        src_of[d] = c;
    }
}

// ---------------------------------------------------------------------------
// Kernel 1 (R4-verified): quantize. b<256: x -> qX (i8) + sX + S0X (seg0
// rowsum). b>=256: W -> qWp (packed) + sW. Seg0 nibbles +8-biased at byte
// b0 = (t>>3)*64 + (t&3)*16 + ((t>>2)&1)*8  (fragment-contiguous for GEMM).
// ---------------------------------------------------------------------------
__global__ __launch_bounds__(256) void quant_k(const float* __restrict__ x,
                                               const float* __restrict__ W,
                                               const int* __restrict__ src_of,
                                               int8_t* __restrict__ qX,
                                               uint8_t* __restrict__ qWp,
                                               float* __restrict__ sX,
                                               float* __restrict__ sW,
                                               int* __restrict__ S0X) {
    __shared__ float rowbuf[KF];
    __shared__ float lmax[256];
    __shared__ float sm[3];
    __shared__ int isum[256];
    const int b = blockIdx.x;
    const int t = threadIdx.x;
    const int w = t >> 6, lane = t & 63;
    const bool isX = b < T_ROWS;
    const int r = isX ? b : b - T_ROWS;
    const float* row = (isX ? x : W) + (size_t)r * KF;

#pragma unroll
    for (int j = 0; j < 4; ++j) {
        const uint8_t* src = (const uint8_t*)(row + j * 1024 + t * 4);
        __builtin_amdgcn_global_load_lds((gptr_t)src, (lptr_t)&rowbuf[j * 1024 + w * 256], 16, 0, 0);
    }

    const int seg = t < 232 ? 0 : (t < 248 ? 1 : 2);
    const float qmax = seg == 0 ? 7.f : (seg == 1 ? 31.f : 127.f);
    int c[16];
#pragma unroll
    for (int i = 0; i < 4; ++i) {
        v4i ci = *(const v4i*)&src_of[t * 16 + i * 4];
        c[i*4+0] = ci[0]; c[i*4+1] = ci[1]; c[i*4+2] = ci[2]; c[i*4+3] = ci[3];
    }
    __syncthreads();

    float v[16];
    float mx = 0.f;
#pragma unroll
    for (int i = 0; i < 16; ++i) { v[i] = rowbuf[c[i]]; mx = fmaxf(mx, fabsf(v[i])); }
    lmax[t] = mx;
    __syncthreads();
    if (w == 0) {
        float m = fmaxf(fmaxf(lmax[lane], lmax[lane + 64]), lmax[lane + 128]);
        if (lane < 40) m = fmaxf(m, lmax[lane + 192]);
#pragma unroll
        for (int off = 32; off; off >>= 1) m = fmaxf(m, __shfl_xor(m, off));
        if (lane == 0) sm[0] = m;
    } else if (w == 1) {
        float m = lane < 16 ? lmax[232 + lane] : 0.f;
#pragma unroll
        for (int off = 8; off; off >>= 1) m = fmaxf(m, __shfl_xor(m, off));
        if (lane == 0) sm[1] = m;
    } else if (w == 2) {
        float m = lane < 8 ? lmax[248 + lane] : 0.f;
#pragma unroll
        for (int off = 4; off; off >>= 1) m = fmaxf(m, __shfl_xor(m, off));
        if (lane == 0) sm[2] = m;
    }
    __syncthreads();
    float s = sm[seg] / qmax;
    if (s == 0.f) s = 1.f;
    if (t == 0 || t == 232 || t == 248)
        (isX ? sX : sW)[seg * (isX ? T_ROWS : OF) + r] = s;

    int q[16];
#pragma unroll
    for (int i = 0; i < 16; ++i)
        q[i] = (int)rintf(fminf(fmaxf(v[i] / s, -qmax), qmax));  // RNE == np.round

    if (isX) {
        int ss = 0;
        union { int8_t bb[16]; v4i vv; } u;
#pragma unroll
        for (int i = 0; i < 16; ++i) { u.bb[i] = (int8_t)q[i]; ss += q[i]; }
        isum[t] = (seg == 0) ? ss : 0;
        *(v4i*)(qX + (size_t)r * KF + t * 16) = u.vv;
        __syncthreads();
        if (w == 0) {
            int v2 = isum[lane] + isum[lane + 64] + isum[lane + 128] + isum[lane + 192];
#pragma unroll
            for (int off = 32; off; off >>= 1) v2 += __shfl_xor(v2, off);
            if (lane == 0) S0X[r] = v2;
        }
    } else {
        uint8_t* wrow = qWp + (size_t)r * WROW;
        if (seg == 0) {
            u32 pk[2] = {0, 0};
#pragma unroll
            for (int j = 0; j < 8; ++j) {
                u32 byte = (u32)(q[2*j] + 8) | ((u32)(q[2*j+1] + 8) << 4);
                pk[j >> 2] |= byte << ((j & 3) * 8);
            }
            const int b0 = ((t >> 3) * 64) + ((t & 3) * 16) + (((t >> 2) & 1) * 8);
            *(u32*)(wrow + b0) = pk[0];
            *(u32*)(wrow + b0 + 4) = pk[1];
        } else {
            union { int8_t bb[16]; v4i vv; } u;
#pragma unroll
            for (int i = 0; i < 16; ++i) u.bb[i] = (int8_t)q[i];
            *(v4i*)(wrow + 1856 + (t - 232) * 16) = u.vv;
        }
    }
}

// unpack 8 packed bytes (2 dwords, +8-biased nibble pairs) -> 16 i8 [R4-verified]
__device__ __forceinline__ v4i unpack8(u32 d0, u32 d1) {
    v4i r;
    u32 lo0 = d0 & 0x0F0F0F0Fu, hi0 = (d0 >> 4) & 0x0F0F0F0Fu;
    u32 lo1 = d1 & 0x0F0F0F0Fu, hi1 = (d1 >> 4) & 0x0F0F0F0Fu;
    r[0] = (int)__builtin_amdgcn_perm(hi0, lo0, 0x05010400u);
    r[1] = (int)__builtin_amdgcn_perm(hi0, lo0, 0x07030602u);
    r[2] = (int)__builtin_amdgcn_perm(hi1, lo1, 0x05010400u);
    r[3] = (int)__builtin_amdgcn_perm(hi1, lo1, 0x07030602u);
    return r;
}

// ---------------------------------------------------------------------------
// Kernel 2: int8 MFMA GEMM, 128x64 tile, grid 344, 4 waves. 32 K-steps of 128.
// B: PACKED bytes staged via global_load_lds (4 KB/step; 8 KB i8 tail) into a
//    3-slot ring; ds_read_b128 one 16B chunk = both kk fragments; in-register
//    v_perm unpack. ^(row&3) [packed] / ^(row&7) [tail] 16B chunk swizzle,
//    source-side pre-swizzle, linear LDS dest (rule 21).
// A: per-lane global->reg dwordx4 (qX 1 MB, L2-resident), issued 2 steps ahead
//    into the just-freed buffer. Scales/S0X/rowsums preloaded to VGPRs so
//    mid-loop flushes are pure VALU. Counted vmcnt: 5 steady / 6 tail / 0 drain.
// ---------------------------------------------------------------------------
__global__ __launch_bounds__(256, 2)
void gemm_k(const int8_t* __restrict__ qX, const uint8_t* __restrict__ qWp,
            const float* __restrict__ sX, const float* __restrict__ sW,
            const int* __restrict__ S0X,
            const float* __restrict__ bias, float* __restrict__ out) {
    __shared__ __align__(16) int8_t lB[3][8192];

    const int bid = blockIdx.x;
    const int swz = (bid & 7) * 43 + (bid >> 3);  // 344 = 8*43: bijective
    const int row0 = (swz & 1) * 128;
    const int col0 = (swz >> 1) * 64;
    const int tid = threadIdx.x;
    const int lane = tid & 63;
    const int w = tid >> 6;
    const int kg = lane >> 4;     // 0..3: K-chunk group
    const int cr = lane & 15;     // row/col within fragment

    v4i iacc[2][4];
    v4f facc[2][4];
#pragma unroll
    for (int m = 0; m < 2; ++m)
#pragma unroll
        for (int n = 0; n < 4; ++n) {
            iacc[m][n][0]=0; iacc[m][n][1]=0; iacc[m][n][2]=0; iacc[m][n][3]=0;
            facc[m][n][0]=0.f; facc[m][n][1]=0.f; facc[m][n][2]=0.f; facc[m][n][3]=0.f;
        }

    // ---- preload all flush constants into VGPRs (forces waits here, once) ----
    float sa_r[3][2][4]; int s0_r[2][4]; float sb_r[3][4];
#pragma unroll
    for (int m = 0; m < 2; ++m)
#pragma unroll
        for (int rr = 0; rr < 4; ++rr) {
            const int rg = row0 + w * 32 + m * 16 + ((lane >> 4) << 2) + rr;
#pragma unroll
            for (int seg = 0; seg < 3; ++seg) { sa_r[seg][m][rr] = sX[seg * T_ROWS + rg]; KEEPF(sa_r[seg][m][rr]); }
            s0_r[m][rr] = S0X[rg]; KEEPI(s0_r[m][rr]);
        }
#pragma unroll
    for (int n = 0; n < 4; ++n) {
        const int cg = col0 + n * 16 + (lane & 15);
#pragma unroll
        for (int seg = 0; seg < 3; ++seg) { sb_r[seg][n] = sW[seg * OF + cg]; KEEPF(sb_r[seg][n]); }
    }

    const int8_t* aRow[2];
    aRow[0] = qX + (size_t)(row0 + w * 32 + cr) * KF;
    aRow[1] = qX + (size_t)(row0 + w * 32 + 16 + cr) * KF;

    auto stageB = [&](int slot, int step) {
        if (step <= 28) {  // packed: 64 rows x 64 B, 1 instr/thread
            const int brow = w * 16 + (lane >> 2);
            const int sc = ((lane & 3) ^ (brow & 3)) << 4;
            const uint8_t* src = qWp + (size_t)(col0 + brow) * WROW + step * 64 + sc;
            __builtin_amdgcn_global_load_lds((gptr_t)src, (lptr_t)&lB[slot][w * 1024], 16, 0, 0);
        } else {           // i8 tail: 64 rows x 128 B, 2 instr/thread
            const int off = 1856 + (step - 29) * 128;
#pragma unroll
            for (int j = 0; j < 2; ++j) {
                const int brow = j * 32 + w * 8 + (lane >> 3);
                const int sc = ((lane & 7) ^ (brow & 7)) << 4;
                const uint8_t* src = qWp + (size_t)(col0 + brow) * WROW + off + sc;
                __builtin_amdgcn_global_load_lds((gptr_t)src, (lptr_t)&lB[slot][j * 4096 + w * 1024], 16, 0, 0);
            }
        }
    };

    auto loadA = [&](v4i (&a)[2][2], int step) {
        const int kb = step * 128 + kg * 16;
#pragma unroll
        for (int m = 0; m < 2; ++m)
#pragma unroll
            for (int kk = 0; kk < 2; ++kk) {
                const int8_t* p = aRow[m] + kb + kk * 64;
                asm volatile("global_load_dwordx4 %0, %1, off"
                             : "=v"(a[m][kk]) : "v"(p) : "memory");
            }
    };

    auto flush = [&](int seg) {  // pure VALU (all inputs preloaded)
#pragma unroll
        for (int m = 0; m < 2; ++m)
#pragma unroll
            for (int n = 0; n < 4; ++n)
#pragma unroll
                for (int rr = 0; rr < 4; ++rr) {
                    const int v = iacc[m][n][rr] - ((seg == 0) ? 8 * s0_r[m][rr] : 0);
                    facc[m][n][rr] += (float)v * (sa_r[seg][m][rr] * sb_r[seg][n]);
                    iacc[m][n][rr] = 0;
                }
    };

    auto body = [&](int t, v4i (&aCur)[2][2]) {
        __builtin_amdgcn_s_barrier();
        v4i bf[4][2];
        const int8_t* pb = &lB[t % 3][0];
        if (t <= 28) {
#pragma unroll
            for (int n = 0; n < 4; ++n) {
                const int brow = n * 16 + cr;
                v4i pk = *(const v4i*)(pb + brow * 64 + ((kg ^ (brow & 3)) << 4));
                bf[n][0] = unpack8((u32)pk[0], (u32)pk[1]);
                bf[n][1] = unpack8((u32)pk[2], (u32)pk[3]);
            }
        } else {
#pragma unroll
            for (int n = 0; n < 4; ++n) {
                const int brow = n * 16 + cr;
#pragma unroll
                for (int kk = 0; kk < 2; ++kk) {
                    const int ch = (kk * 4 + kg) ^ (brow & 7);
                    bf[n][kk] = *(const v4i*)(pb + brow * 128 + ch * 16);
                }
            }
        }
        if (t + 2 < 32) stageB((t + 2) % 3, t + 2);
        asm volatile("s_waitcnt lgkmcnt(0)" ::: "memory");
        __builtin_amdgcn_sched_barrier(0);
#pragma unroll
        for (int kk = 0; kk < 2; ++kk)
#pragma unroll
            for (int m = 0; m < 2; ++m)
#pragma unroll
                for (int n = 0; n < 4; ++n)
                    iacc[m][n] = __builtin_amdgcn_mfma_i32_16x16x64_i8(aCur[m][kk], bf[n][kk], iacc[m][n], 0, 0, 0);
        if (t == 28) flush(0);          // seg0: K [0,3712)
        else if (t == 30) flush(1);     // seg1: K [3712,3968)
        if (t + 2 < 32) loadA(aCur, t + 2);   // into just-freed buffer
        // retire stageB(t+1) + loadA(t+1); keep stageB(t+2) + loadA(t+2)
        if (t <= 26)      asm volatile("s_waitcnt vmcnt(5)" ::: "memory");
        else if (t <= 29) asm volatile("s_waitcnt vmcnt(6)" ::: "memory");
        else              asm volatile("s_waitcnt vmcnt(0)" ::: "memory");
    };

    v4i aA[2][2], aB[2][2];
    loadA(aA, 0);
    stageB(0, 0);
    stageB(1, 1);
    loadA(aB, 1);
    asm volatile("s_waitcnt vmcnt(5)" ::: "memory");   // A(0), B(0) landed

    for (int tt = 0; tt < 32; tt += 2) {
        body(tt,     aA);
        body(tt + 1, aB);
    }
    flush(2);                           // seg2: K [3968,4096)

#pragma unroll
    for (int m = 0; m < 2; ++m)
#pragma unroll
        for (int n = 0; n < 4; ++n) {
            const int colg = col0 + n * 16 + (lane & 15);
            const float bv = bias[colg];
#pragma unroll
            for (int rr = 0; rr < 4; ++rr) {
                const int rowg = row0 + w * 32 + m * 16 + ((lane >> 4) << 2) + rr;
                out[(size_t)rowg * OF + colg] = facc[m][n][rr] + bv;
            }
        }
}

// ---------------------------------------------------------------------------
// workspace layout (bytes):
//   qX     @ 0          :  1,048,576
//   qWp    @ 1,048,576  : 24,657,920   (11008 x 2240)
//   sX     @ 25,706,496 :      3,072
//   sW     @ 25,709,568 :    132,096
//   src_of @ 25,841,664 :     16,384
//   S0X    @ 25,858,048 :      1,024
// ---------------------------------------------------------------------------
extern "C" void kernel_launch(void* const* d_in, const int* in_sizes, int n_in,
                              void* d_out, int out_size, void* d_ws, size_t ws_size,
                              hipStream_t stream) {
    const float* x    = (const float*)d_in[0];
    const float* W    = (const float*)d_in[1];
    const float* bias = (const float*)d_in[2];
    const int*   ridx = (const int*)d_in[3];
    float* out = (float*)d_out;

    uint8_t* ws = (uint8_t*)d_ws;
    int8_t*  qX  = (int8_t*)ws;
    uint8_t* qWp = ws + 1048576;
    float*   sX  = (float*)(ws + 25706496);
    float*   sW  = (float*)(ws + 25709568);
    int* src_of  = (int*)(ws + 25841664);
    int* S0X     = (int*)(ws + 25858048);

    perm_k<<<1, 256, 0, stream>>>(ridx, src_of);
    quant_k<<<T_ROWS + OF, 256, 0, stream>>>(x, W, src_of, qX, qWp, sX, sW, S0X);
    gemm_k<<<344, 256, 0, stream>>>(qX, qWp, sX, sW, S0X, bias, out);
}